// Round 14
// baseline (17.624 us; speedup 1.0000x reference)
//
#include <hip/hip_runtime.h>
#include <math.h>

constexpr int kB = 2, kP = 300, kF = 512, kH = 128, kW = 128, kTH = 512, kTW = 512;
constexpr float kDelta = 7000.0f;
constexpr float kCut = 0.0363f;    // skip p < ~1e-4 contributions (improb err <= ~1e-3)
constexpr float kThr2 = 0.012928f; // (kCut + 0.0774 pixel-center tile radius)^2
constexpr float kIntThr = 0.0785f; // minL(center) >= this -> ALL pixels inside
constexpr float kLogInside = -15.9423847f; // log1p(-(1-1e-7f)) = ln(2^-23)

__device__ __forceinline__ unsigned zmap(float f) {
    unsigned b = __float_as_uint(f);
    return (b & 0x80000000u) ? ~b : (b | 0x80000000u);  // order-preserving float->uint
}

// One fused kernel. Grid: 512 blocks = 2 batches x 256 tiles (8x8 px).
// Block: 512 threads = 8 waves. RAW face f dealt to slot (f&7)*64+(f>>3):
// wave wv owns slots [wv*64,wv*64+64) = faces f===wv (mod 8). Backfaces get
// sentinel L-rows -> ballot-culled with zero loop cost (no compaction, 1 barrier).
// Per-face LDS records (8 x float4):
//  F0=(A0,B0,C0,A1) F1=(B1,C1,A2,B2) F2=(C2,az,bz,cz)   L_i = unit-normal line dist
//  F3=(T0x,T0y,T0c,len0) F4=(T1..) F5=(T2..)            s_i = tangential affine
//  F6=(ua,ub,uc,-) F7=(va,vb,vc,-)                      u,v affine
// seg_i dist^2 = L_i^2 (if s_i in [0,len_i]); vertex dist^2 = L_i^2 + s_i^2.
// Edge loop: BRANCHLESS, 2 faces per trip (ILP over LDS latency).
__global__ __launch_bounds__(512, 4) void render_all(const float* __restrict__ pts,
                                                     const int* __restrict__ faces,
                                                     const float* __restrict__ uvs,
                                                     const float* __restrict__ tex,
                                                     float* __restrict__ out) {
    __shared__ float4 sF[8][kF];                   // 64 KB
    __shared__ unsigned long long s_best[64];      // packed (zmap | 511-f)
    __shared__ float s_lm[64];
    float4* s_pxW = sF[0];                         // aliases (F0 dead post-loop)
    int4* s_pxO = (int4*)(sF[0] + 64);

    int tile = (int)blockIdx.x;
    int b = tile >> 8;
    int rem = tile & 255;
    int ty = rem >> 4, tx = rem & 15;
    int tid = (int)threadIdx.x;
    int lane = tid & 63;
    int wv = tid >> 6;

    // ---------- setup: thread tid = face tid; ONE barrier ----------
    {
        int f = tid;
        int i0 = faces[f * 3 + 0], i1 = faces[f * 3 + 1], i2 = faces[f * 3 + 2];
        const float* pb = pts + b * kP * 3;
        float x0 = pb[i0 * 3], y0 = pb[i0 * 3 + 1], z0 = pb[i0 * 3 + 2];
        float x1 = pb[i1 * 3], y1 = pb[i1 * 3 + 1], z1 = pb[i1 * 3 + 2];
        float x2 = pb[i2 * 3], y2 = pb[i2 * 3 + 1], z2 = pb[i2 * 3 + 2];
        const float* ub = uvs + b * (kP * 2);
        float u0 = ub[i0 * 2], vv0 = ub[i0 * 2 + 1];
        float u1 = ub[i1 * 2], vv1 = ub[i1 * 2 + 1];
        float u2 = ub[i2 * 2], vv2 = ub[i2 * 2 + 1];
        float area = (x1 - x0) * (y2 - y0) - (y1 - y0) * (x2 - x0);
        bool front = area > 1e-8f;

        if (tid < 64) { s_best[tid] = 0ull; s_lm[tid] = 0.0f; }

        int slot = ((f & 7) << 6) | (f >> 3);  // deal raw faces across waves
        float inv_a = front ? (1.0f / area) : 0.0f;
        float e0x = x2 - x1, e0y = y2 - y1;
        float e1x = x0 - x2, e1y = y0 - y2;
        float e2x = x1 - x0, e2y = y1 - y0;
        float l0 = fmaf(e0x, e0x, e0y * e0y);
        float l1 = fmaf(e1x, e1x, e1y * e1y);
        float l2 = fmaf(e2x, e2x, e2y * e2y);
        float s0 = rsqrtf(l0 + 1e-12f);
        float s1 = rsqrtf(l1 + 1e-12f);
        float s2 = rsqrtf(l2 + 1e-12f);
        float A0 = -e0y * s0, B0 = e0x * s0, C0 = (e0y * x1 - e0x * y1) * s0;
        float A1 = -e1y * s1, B1 = e1x * s1, C1 = (e1y * x2 - e1x * y2) * s1;
        float A2 = -e2y * s2, B2 = e2x * s2, C2 = (e2y * x0 - e2x * y0) * s2;
        float a0 = -e0y * inv_a, b0 = e0x * inv_a, c0 = (e0y * x1 - e0x * y1) * inv_a;
        float a1 = -e1y * inv_a, b1 = e1x * inv_a, c1 = (e1y * x2 - e1x * y2) * inv_a;
        float a2 = -e2y * inv_a, b2 = e2x * inv_a, c2 = (e2y * x0 - e2x * y0) * inv_a;
        if (front) {
            sF[0][slot] = make_float4(A0, B0, C0, A1);
            sF[1][slot] = make_float4(B1, C1, A2, B2);
            sF[2][slot] = make_float4(C2,
                                      a0 * z0 + a1 * z1 + a2 * z2,
                                      b0 * z0 + b1 * z1 + b2 * z2,
                                      c0 * z0 + c1 * z1 + c2 * z2);
        } else {  // sentinel: L0=L1=L2=-1e30 -> never inside/inter/admitted
            sF[0][slot] = make_float4(0.0f, 0.0f, -1e30f, 0.0f);
            sF[1][slot] = make_float4(0.0f, -1e30f, 0.0f, 0.0f);
            sF[2][slot] = make_float4(-1e30f, 0.0f, 0.0f, 0.0f);
        }
        // finite for all faces (degenerate-safe via +1e-12)
        sF[3][slot] = make_float4(e0x * s0, e0y * s0,
                                  -(e0x * x1 + e0y * y1) * s0, l0 * s0);  // from v1
        sF[4][slot] = make_float4(e1x * s1, e1y * s1,
                                  -(e1x * x2 + e1y * y2) * s1, l1 * s1);  // from v2
        sF[5][slot] = make_float4(e2x * s2, e2y * s2,
                                  -(e2x * x0 + e2y * y0) * s2, l2 * s2);  // from v0
        sF[6][slot] = make_float4(a0 * u0 + a1 * u1 + a2 * u2,
                                  b0 * u0 + b1 * u1 + b2 * u2,
                                  c0 * u0 + c1 * u1 + c2 * u2, 0.0f);
        sF[7][slot] = make_float4(a0 * vv0 + a1 * vv1 + a2 * vv2,
                                  b0 * vv0 + b1 * vv1 + b2 * vv2,
                                  c0 * vv0 + c1 * vv1 + c2 * vv2, 0.0f);
    }
    __syncthreads();

    // ---------- render ----------
    int pyi = ty * 8 + (lane >> 3);
    int pxi = tx * 8 + (lane & 7);
    float px = ((float)pxi + 0.5f) * (2.0f / 128.0f) - 1.0f;
    float py = 1.0f - ((float)pyi + 0.5f) * (2.0f / 128.0f);

    // cull at tile center: exact dist-to-triangle via L/s identities
    float cx = (float)(tx * 8 + 4) * (2.0f / 128.0f) - 1.0f;
    float cy = 1.0f - (float)(ty * 8 + 4) * (2.0f / 128.0f);
    unsigned long long me, mi;
    {
        int slt = (wv << 6) + lane;
        float4 a4 = sF[0][slt];
        float4 b4 = sF[1][slt];
        float4 c4 = sF[2][slt];
        float4 t0 = sF[3][slt];
        float4 t1 = sF[4][slt];
        float4 t2 = sF[5][slt];
        float L0 = fmaf(a4.x, cx, fmaf(a4.y, cy, a4.z));
        float L1 = fmaf(a4.w, cx, fmaf(b4.x, cy, b4.y));
        float L2 = fmaf(b4.z, cx, fmaf(b4.w, cy, c4.x));
        float minc = fminf(fminf(L0, L1), L2);
        float s0 = fmaf(t0.x, cx, fmaf(t0.y, cy, t0.z));
        float s1 = fmaf(t1.x, cx, fmaf(t1.y, cy, t1.z));
        float s2 = fmaf(t2.x, cx, fmaf(t2.y, cy, t2.z));
        float q0 = L0 * L0, q1 = L1 * L1, q2 = L2 * L2;
        float c0 = (s0 >= 0.0f && s0 <= t0.w) ? q0 : 1e30f;
        float c1 = (s1 >= 0.0f && s1 <= t1.w) ? q1 : 1e30f;
        float c2 = (s2 >= 0.0f && s2 <= t2.w) ? q2 : 1e30f;
        float dv1 = fmaf(s0, s0, q0);
        float dv2 = fmaf(s1, s1, q1);
        float dv0 = fmaf(s2, s2, q2);
        float d2c = fminf(fminf(fminf(c0, c1), fminf(c2, dv0)), fminf(dv1, dv2));
        bool inter = minc >= kIntThr;
        bool admit = (minc >= 0.0f) | (d2c <= kThr2);
        mi = __ballot(inter);
        me = __ballot(admit && !inter);
    }

    float bestz = -1e9f;
    int besti = 1 << 30, icnt = 0;
    float lm = 0.0f;

    // interior loop: z-argmax only
    icnt += (int)__popcll(mi);
    while (mi) {
        int l = (int)__builtin_ctzll(mi);
        mi &= (mi - 1);
        bool two = mi != 0;
        int l2 = two ? (int)__builtin_ctzll(mi) : l;
        if (two) mi &= (mi - 1);
        float4 hA = sF[2][(wv << 6) + l];
        float4 hB = sF[2][(wv << 6) + l2];
        int kA = (l << 3) | wv, kB = (l2 << 3) | wv;
        float zA = fmaf(hA.y, px, fmaf(hA.z, py, hA.w));
        float zB = fmaf(hB.y, px, fmaf(hB.z, py, hB.w));
        if (zA > bestz || (zA == bestz && kA < besti)) { bestz = zA; besti = kA; }
        if (zB > bestz || (zB == bestz && kB < besti)) { bestz = zB; besti = kB; }
    }

    // edge loop: branchless, 2 faces per trip
    while (me) {
        int la = (int)__builtin_ctzll(me);
        me &= (me - 1);
        bool two = me != 0;
        int lb = two ? (int)__builtin_ctzll(me) : la;
        if (two) me &= (me - 1);
        int fsa = (wv << 6) + la, fsb = (wv << 6) + lb;
        int ka = (la << 3) | wv, kb = (lb << 3) | wv;
        float4 Ah0 = sF[0][fsa], Ah1 = sF[1][fsa], Ah2 = sF[2][fsa];
        float4 At0 = sF[3][fsa], At1 = sF[4][fsa], At2 = sF[5][fsa];
        float4 Bh0 = sF[0][fsb], Bh1 = sF[1][fsb], Bh2 = sF[2][fsb];
        float4 Bt0 = sF[3][fsb], Bt1 = sF[4][fsb], Bt2 = sF[5][fsb];

        // face A
        {
            float L0 = fmaf(Ah0.x, px, fmaf(Ah0.y, py, Ah0.z));
            float L1 = fmaf(Ah0.w, px, fmaf(Ah1.x, py, Ah1.y));
            float L2 = fmaf(Ah1.z, px, fmaf(Ah1.w, py, Ah2.x));
            bool inside = fminf(fminf(L0, L1), L2) >= 0.0f;
            float z = fmaf(Ah2.y, px, fmaf(Ah2.z, py, Ah2.w));
            if (inside && (z > bestz || (z == bestz && ka < besti))) { bestz = z; besti = ka; }
            icnt += inside ? 1 : 0;
            float s0 = fmaf(At0.x, px, fmaf(At0.y, py, At0.z));
            float s1 = fmaf(At1.x, px, fmaf(At1.y, py, At1.z));
            float s2 = fmaf(At2.x, px, fmaf(At2.y, py, At2.z));
            float q0 = L0 * L0, q1 = L1 * L1, q2 = L2 * L2;
            float c0 = (s0 >= 0.0f && s0 <= At0.w) ? q0 : 1e30f;
            float c1 = (s1 >= 0.0f && s1 <= At1.w) ? q1 : 1e30f;
            float c2 = (s2 >= 0.0f && s2 <= At2.w) ? q2 : 1e30f;
            float d2 = fminf(fminf(fminf(c0, c1), fminf(c2, fmaf(s2, s2, q2))),
                             fminf(fmaf(s0, s0, q0), fmaf(s1, s1, q1)));
            bool need = (!inside) &
                        (fminf(fminf(fabsf(L0), fabsf(L1)), fabsf(L2)) < kCut);
            d2 = need ? d2 : 30.0f;       // exp(-7000*30)==0 -> log(1)==0
            float p = fminf(__expf(-kDelta * d2), 1.0f - 1e-7f);
            lm += __logf(1.0f - p);
        }
        // face B (masked when !two; la==lb then, and d2->30 contributes 0)
        {
            float L0 = fmaf(Bh0.x, px, fmaf(Bh0.y, py, Bh0.z));
            float L1 = fmaf(Bh0.w, px, fmaf(Bh1.x, py, Bh1.y));
            float L2 = fmaf(Bh1.z, px, fmaf(Bh1.w, py, Bh2.x));
            bool inside = (fminf(fminf(L0, L1), L2) >= 0.0f) && two;
            float z = fmaf(Bh2.y, px, fmaf(Bh2.z, py, Bh2.w));
            if (inside && (z > bestz || (z == bestz && kb < besti))) { bestz = z; besti = kb; }
            icnt += inside ? 1 : 0;
            float s0 = fmaf(Bt0.x, px, fmaf(Bt0.y, py, Bt0.z));
            float s1 = fmaf(Bt1.x, px, fmaf(Bt1.y, py, Bt1.z));
            float s2 = fmaf(Bt2.x, px, fmaf(Bt2.y, py, Bt2.z));
            float q0 = L0 * L0, q1 = L1 * L1, q2 = L2 * L2;
            float c0 = (s0 >= 0.0f && s0 <= Bt0.w) ? q0 : 1e30f;
            float c1 = (s1 >= 0.0f && s1 <= Bt1.w) ? q1 : 1e30f;
            float c2 = (s2 >= 0.0f && s2 <= Bt2.w) ? q2 : 1e30f;
            float d2 = fminf(fminf(fminf(c0, c1), fminf(c2, fmaf(s2, s2, q2))),
                             fminf(fmaf(s0, s0, q0), fmaf(s1, s1, q1)));
            bool need = (!inside) && two &&
                        (fminf(fminf(fabsf(L0), fabsf(L1)), fabsf(L2)) < kCut);
            d2 = need ? d2 : 30.0f;
            float p = fminf(__expf(-kDelta * d2), 1.0f - 1e-7f);
            lm += __logf(1.0f - p);
        }
    }
    lm = fmaf((float)icnt, kLogInside, lm);

    // merge via LDS atomics: key = (zmap(z) << 32) | (511 - f); max => first-max
    if (besti < (1 << 30)) {
        unsigned long long key = ((unsigned long long)zmap(bestz) << 32) |
                                 (unsigned long long)(511 - besti);
        atomicMax(&s_best[lane], key);
    }
    atomicAdd(&s_lm[lane], lm);
    __syncthreads();

    // ---------- reduce + fragment prep (wave 0) ----------
    if (tid < 64) {
        unsigned long long key = s_best[tid];
        float improb = 1.0f - expf(s_lm[tid]);
        float u = 0.0f, v = 0.0f, mk = 0.0f;
        if (key != 0ull) {
            int bi = 511 - (int)(key & 0xFFFFFFFFull);       // original face idx
            int slot = ((bi & 7) << 6) | (bi >> 3);
            float4 uq = sF[6][slot];
            float4 vq = sF[7][slot];
            u = fmaf(uq.x, px, fmaf(uq.y, py, uq.z));
            v = fmaf(vq.x, px, fmaf(vq.y, py, vq.z));
            mk = 1.0f;  // mask = w0+w1+w2 == 1 exactly (err ~2e-7)
        }
        float uc = fminf(fmaxf(u, 0.0f), 1.0f);
        float vc = fminf(fmaxf(v, 0.0f), 1.0f);
        float fx = uc * (float)(kTW - 1);
        float fy = (1.0f - vc) * (float)(kTH - 1);
        int xi0 = (int)floorf(fx), yi0 = (int)floorf(fy);
        int xi1 = min(xi0 + 1, kTW - 1), yi1 = min(yi0 + 1, kTH - 1);
        float wx = fx - (float)xi0, wy = fy - (float)yi0;
        float w00 = (1.0f - wx) * (1.0f - wy) * mk;
        float w01 = wx * (1.0f - wy) * mk;
        float w10 = (1.0f - wx) * wy * mk;
        float w11 = wx * wy * mk;
        s_pxW[tid] = make_float4(w00, w01, w10, w11);   // aliases F0 (dead)
        s_pxO[tid] = make_int4(yi0 * kTW + xi0, yi0 * kTW + xi1,
                               yi1 * kTW + xi0, yi1 * kTW + xi1);
        out[kB * kH * kW * 3 + (b * kH + pyi) * kW + pxi] = improb;
    }
    __syncthreads();

    // ---------- fragment shader: 192 threads = 64 px x 3 channels ----------
    if (tid < 192) {
        int pix = tid & 63;
        int c = tid >> 6;
        float4 w = s_pxW[pix];
        int4 o = s_pxO[pix];
        const float* tc = tex + ((size_t)b * 3 + c) * kTH * kTW;
        float col = tc[o.x] * w.x + tc[o.y] * w.y + tc[o.z] * w.z + tc[o.w] * w.w;
        int qy = ty * 8 + (pix >> 3);
        int qx = tx * 8 + (pix & 7);
        out[((b * kH + qy) * kW + qx) * 3 + c] = col;
    }
}

extern "C" void kernel_launch(void* const* d_in, const int* in_sizes, int n_in,
                              void* d_out, int out_size, void* d_ws, size_t ws_size,
                              hipStream_t stream) {
    const float* pts = (const float*)d_in[0];
    const int* faces = (const int*)d_in[1];
    const float* uvs = (const float*)d_in[2];
    const float* tex = (const float*)d_in[3];
    float* out = (float*)d_out;
    render_all<<<kB * 256, 512, 0, stream>>>(pts, faces, uvs, tex, out);
}

// Round 15
// 17.272 us; speedup vs baseline: 1.0204x; 1.0204x over previous
//
#include <hip/hip_runtime.h>
#include <math.h>

constexpr int kB = 2, kP = 300, kF = 512, kH = 128, kW = 128, kTH = 512, kTW = 512;
constexpr float kDelta = 7000.0f;
constexpr float kCut = 0.0363f;    // skip p < ~1e-4 contributions (improb err <= ~1e-3)
constexpr float kThr2 = 0.012928f; // (kCut + 0.0774 pixel-center tile radius)^2
constexpr float kIntThr = 0.0785f; // minL(center) >= this -> ALL pixels inside
constexpr float kLogInside = -15.9423847f; // log1p(-(1-1e-7f)) = ln(2^-23)

__device__ __forceinline__ unsigned zmap(float f) {
    unsigned b = __float_as_uint(f);
    return (b & 0x80000000u) ? ~b : (b | 0x80000000u);  // order-preserving float->uint
}

// R12 configuration (best measured: 17.25 us) — reverted from R13's regression.
// One fused kernel. Grid: 512 blocks = 2 batches x 256 tiles (8x8 px).
// Block: 512 threads = 8 waves. Compacted front-face k DEALT to slot
// (k&7)*64+(k>>3); wave wv owns slots [wv*64,wv*64+64) = faces k===wv (mod 8).
// Per-face LDS records (8 x float4):
//  F0=(A0,B0,C0,A1) F1=(B1,C1,A2,B2) F2=(C2,az,bz,cz)   L_i = unit-normal line dist
//  F3=(T0x,T0y,T0c,len0) F4=(T1..) F5=(T2..)            s_i = tangential affine
//  F6=(ua,ub,uc,-) F7=(va,vb,vc,-)                      u,v affine
// Identities: seg_i dist^2 = L_i^2 (if s_i in [0,len_i]); vertex dist^2 = L_i^2+s_i^2.
// Edge loop is BRANCHLESS: non-band faces get d2=30 -> exp -> 0 -> log(1)=0.
__global__ __launch_bounds__(512, 4) void render_all(const float* __restrict__ pts,
                                                     const int* __restrict__ faces,
                                                     const float* __restrict__ uvs,
                                                     const float* __restrict__ tex,
                                                     float* __restrict__ out) {
    __shared__ float4 sF[8][kF];                   // 64 KB
    __shared__ unsigned long long s_best[64];      // 512 B packed (z | 511-k)
    __shared__ float s_lm[64];                     // 256 B log-miss accum
    __shared__ int s_wsum[8];
    float4* s_pxW = sF[0];                         // aliases (F0 dead post-loop)
    int4* s_pxO = (int4*)(sF[0] + 64);

    int tile = (int)blockIdx.x;
    int b = tile >> 8;
    int rem = tile & 255;
    int ty = rem >> 4, tx = rem & 15;
    int tid = (int)threadIdx.x;
    int lane = tid & 63;
    int wv = tid >> 6;

    // ---------- setup: thread tid processes face tid for batch b ----------
    {
        int f = tid;
        int i0 = faces[f * 3 + 0], i1 = faces[f * 3 + 1], i2 = faces[f * 3 + 2];
        const float* pb = pts + b * kP * 3;
        float x0 = pb[i0 * 3], y0 = pb[i0 * 3 + 1], z0 = pb[i0 * 3 + 2];
        float x1 = pb[i1 * 3], y1 = pb[i1 * 3 + 1], z1 = pb[i1 * 3 + 2];
        float x2 = pb[i2 * 3], y2 = pb[i2 * 3 + 1], z2 = pb[i2 * 3 + 2];
        const float* ub = uvs + b * (kP * 2);
        float u0 = ub[i0 * 2], vv0 = ub[i0 * 2 + 1];
        float u1 = ub[i1 * 2], vv1 = ub[i1 * 2 + 1];
        float u2 = ub[i2 * 2], vv2 = ub[i2 * 2 + 1];
        float area = (x1 - x0) * (y2 - y0) - (y1 - y0) * (x2 - x0);
        bool front = area > 1e-8f;

        if (tid < 64) { s_best[tid] = 0ull; s_lm[tid] = 0.0f; }
        // prefill rows F0..F2: empty slots -> L=-1e30 (never inside/admitted);
        // cull's fminf chain drops NaN garbage from uninitialized F3..F5.
        sF[0][f] = make_float4(0.0f, 0.0f, -1e30f, 0.0f);
        sF[1][f] = make_float4(0.0f, -1e30f, 0.0f, 0.0f);
        sF[2][f] = make_float4(-1e30f, 0.0f, 0.0f, 0.0f);
        unsigned long long bal = __ballot(front);
        if (lane == 0) s_wsum[wv] = __popcll(bal);
        __syncthreads();  // wsum + prefill + inits visible

        int base = 0;
#pragma unroll
        for (int w = 0; w < 8; ++w) base += (w < wv) ? s_wsum[w] : 0;
        int k = base + __popcll(bal & ((1ull << lane) - 1ull));  // compacted idx

        if (front) {
            int slot = ((k & 7) << 6) | (k >> 3);  // deal across waves
            float inv_a = 1.0f / area;
            float e0x = x2 - x1, e0y = y2 - y1;
            float e1x = x0 - x2, e1y = y0 - y2;
            float e2x = x1 - x0, e2y = y1 - y0;
            float l0 = fmaf(e0x, e0x, e0y * e0y);
            float l1 = fmaf(e1x, e1x, e1y * e1y);
            float l2 = fmaf(e2x, e2x, e2y * e2y);
            float s0 = rsqrtf(l0 + 1e-12f);
            float s1 = rsqrtf(l1 + 1e-12f);
            float s2 = rsqrtf(l2 + 1e-12f);
            float A0 = -e0y * s0, B0 = e0x * s0, C0 = (e0y * x1 - e0x * y1) * s0;
            float A1 = -e1y * s1, B1 = e1x * s1, C1 = (e1y * x2 - e1x * y2) * s1;
            float A2 = -e2y * s2, B2 = e2x * s2, C2 = (e2y * x0 - e2x * y0) * s2;
            float a0 = -e0y * inv_a, b0 = e0x * inv_a, c0 = (e0y * x1 - e0x * y1) * inv_a;
            float a1 = -e1y * inv_a, b1 = e1x * inv_a, c1 = (e1y * x2 - e1x * y2) * inv_a;
            float a2 = -e2y * inv_a, b2 = e2x * inv_a, c2 = (e2y * x0 - e2x * y0) * inv_a;
            sF[0][slot] = make_float4(A0, B0, C0, A1);
            sF[1][slot] = make_float4(B1, C1, A2, B2);
            sF[2][slot] = make_float4(C2,
                                      a0 * z0 + a1 * z1 + a2 * z2,
                                      b0 * z0 + b1 * z1 + b2 * z2,
                                      c0 * z0 + c1 * z1 + c2 * z2);
            // tangential affines: s_i(p) = T_i . p + Tc_i, measured from edge start
            sF[3][slot] = make_float4(e0x * s0, e0y * s0,
                                      -(e0x * x1 + e0y * y1) * s0, l0 * s0);  // from v1
            sF[4][slot] = make_float4(e1x * s1, e1y * s1,
                                      -(e1x * x2 + e1y * y2) * s1, l1 * s1);  // from v2
            sF[5][slot] = make_float4(e2x * s2, e2y * s2,
                                      -(e2x * x0 + e2y * y0) * s2, l2 * s2);  // from v0
            sF[6][slot] = make_float4(a0 * u0 + a1 * u1 + a2 * u2,
                                      b0 * u0 + b1 * u1 + b2 * u2,
                                      c0 * u0 + c1 * u1 + c2 * u2, 0.0f);
            sF[7][slot] = make_float4(a0 * vv0 + a1 * vv1 + a2 * vv2,
                                      b0 * vv0 + b1 * vv1 + b2 * vv2,
                                      c0 * vv0 + c1 * vv1 + c2 * vv2, 0.0f);
        }
    }
    __syncthreads();

    // ---------- render ----------
    int pyi = ty * 8 + (lane >> 3);
    int pxi = tx * 8 + (lane & 7);
    float px = ((float)pxi + 0.5f) * (2.0f / 128.0f) - 1.0f;
    float py = 1.0f - ((float)pyi + 0.5f) * (2.0f / 128.0f);

    // cull at tile center: exact dist-to-triangle via L/s identities
    float cx = (float)(tx * 8 + 4) * (2.0f / 128.0f) - 1.0f;
    float cy = 1.0f - (float)(ty * 8 + 4) * (2.0f / 128.0f);
    unsigned long long me, mi;
    {
        int slt = (wv << 6) + lane;
        float4 a4 = sF[0][slt];
        float4 b4 = sF[1][slt];
        float4 c4 = sF[2][slt];
        float4 t0 = sF[3][slt];
        float4 t1 = sF[4][slt];
        float4 t2 = sF[5][slt];
        float L0 = fmaf(a4.x, cx, fmaf(a4.y, cy, a4.z));
        float L1 = fmaf(a4.w, cx, fmaf(b4.x, cy, b4.y));
        float L2 = fmaf(b4.z, cx, fmaf(b4.w, cy, c4.x));
        float minc = fminf(fminf(L0, L1), L2);
        float s0 = fmaf(t0.x, cx, fmaf(t0.y, cy, t0.z));
        float s1 = fmaf(t1.x, cx, fmaf(t1.y, cy, t1.z));
        float s2 = fmaf(t2.x, cx, fmaf(t2.y, cy, t2.z));
        float q0 = L0 * L0, q1 = L1 * L1, q2 = L2 * L2;
        float c0 = (s0 >= 0.0f && s0 <= t0.w) ? q0 : 1e30f;
        float c1 = (s1 >= 0.0f && s1 <= t1.w) ? q1 : 1e30f;
        float c2 = (s2 >= 0.0f && s2 <= t2.w) ? q2 : 1e30f;
        float dv1 = fmaf(s0, s0, q0);   // dist^2 to v1 (edge0 start)
        float dv2 = fmaf(s1, s1, q1);   // v2
        float dv0 = fmaf(s2, s2, q2);   // v0
        float d2c = fminf(fminf(fminf(c0, c1), fminf(c2, dv0)), fminf(dv1, dv2));
        bool inter = minc >= kIntThr;                       // all 64 px inside
        bool admit = (minc >= 0.0f) | (d2c <= kThr2);
        mi = __ballot(inter);
        me = __ballot(admit && !inter);
    }

    float bestz = -1e9f;
    int besti = 1 << 30, icnt = 0;
    float lm = 0.0f;

    // interior loop: z-argmax only (1 read + ~10 VALU per face)
    icnt += (int)__popcll(mi);   // every pixel inside; lm handled via icnt
    while (mi) {
        int l = (int)__builtin_ctzll(mi);
        mi &= (mi - 1);
        int fs = (wv << 6) + l;
        int k = (l << 3) | wv;
        float4 h2 = sF[2][fs];
        float z = fmaf(h2.y, px, fmaf(h2.z, py, h2.w));
        if (z > bestz || (z == bestz && k < besti)) { bestz = z; besti = k; }
    }

    // edge loop: BRANCHLESS full path (no __any, no per-iteration branch)
    while (me) {
        int l = (int)__builtin_ctzll(me);
        me &= (me - 1);
        int fs = (wv << 6) + l;
        int k = (l << 3) | wv;
        float4 h0 = sF[0][fs];
        float4 h1 = sF[1][fs];
        float4 h2 = sF[2][fs];
        float4 t0 = sF[3][fs];
        float4 t1 = sF[4][fs];
        float4 t2 = sF[5][fs];
        float L0 = fmaf(h0.x, px, fmaf(h0.y, py, h0.z));
        float L1 = fmaf(h0.w, px, fmaf(h1.x, py, h1.y));
        float L2 = fmaf(h1.z, px, fmaf(h1.w, py, h2.x));
        float minL = fminf(fminf(L0, L1), L2);
        bool inside = minL >= 0.0f;
        float z = fmaf(h2.y, px, fmaf(h2.z, py, h2.w));
        if (inside && (z > bestz || (z == bestz && k < besti))) { bestz = z; besti = k; }
        icnt += inside ? 1 : 0;
        float s0 = fmaf(t0.x, px, fmaf(t0.y, py, t0.z));
        float s1 = fmaf(t1.x, px, fmaf(t1.y, py, t1.z));
        float s2 = fmaf(t2.x, px, fmaf(t2.y, py, t2.z));
        float q0 = L0 * L0, q1 = L1 * L1, q2 = L2 * L2;
        float c0 = (s0 >= 0.0f && s0 <= t0.w) ? q0 : 1e30f;
        float c1 = (s1 >= 0.0f && s1 <= t1.w) ? q1 : 1e30f;
        float c2 = (s2 >= 0.0f && s2 <= t2.w) ? q2 : 1e30f;
        float dv1 = fmaf(s0, s0, q0);
        float dv2 = fmaf(s1, s1, q1);
        float dv0 = fmaf(s2, s2, q2);
        float d2 = fminf(fminf(fminf(c0, c1), fminf(c2, dv0)), fminf(dv1, dv2));
        bool need = (!inside) & (fminf(fminf(fabsf(L0), fabsf(L1)), fabsf(L2)) < kCut);
        d2 = need ? d2 : 30.0f;        // exp(-7000*30) == 0 -> log(1-0) == 0
        float p = __expf(-kDelta * d2);
        p = fminf(p, 1.0f - 1e-7f);
        lm += __logf(1.0f - p);        // == log1p(-p) over admitted range
    }
    lm = fmaf((float)icnt, kLogInside, lm);

    // merge via LDS atomics: key = (zmap(z) << 32) | (511 - k); max => first-max
    if (besti < (1 << 30)) {
        unsigned long long key = ((unsigned long long)zmap(bestz) << 32) |
                                 (unsigned long long)(511 - besti);
        atomicMax(&s_best[lane], key);
    }
    atomicAdd(&s_lm[lane], lm);
    __syncthreads();

    // ---------- reduce + fragment prep (wave 0) ----------
    if (tid < 64) {
        unsigned long long key = s_best[tid];
        float improb = 1.0f - expf(s_lm[tid]);
        float u = 0.0f, v = 0.0f, mk = 0.0f;
        if (key != 0ull) {
            int bi = 511 - (int)(key & 0xFFFFFFFFull);
            int slot = ((bi & 7) << 6) | (bi >> 3);
            float4 uq = sF[6][slot];
            float4 vq = sF[7][slot];
            u = fmaf(uq.x, px, fmaf(uq.y, py, uq.z));
            v = fmaf(vq.x, px, fmaf(vq.y, py, vq.z));
            mk = 1.0f;  // mask = w0+w1+w2 == 1 exactly in exact math (err ~2e-7)
        }
        float uc = fminf(fmaxf(u, 0.0f), 1.0f);
        float vc = fminf(fmaxf(v, 0.0f), 1.0f);
        float fx = uc * (float)(kTW - 1);
        float fy = (1.0f - vc) * (float)(kTH - 1);
        int xi0 = (int)floorf(fx), yi0 = (int)floorf(fy);
        int xi1 = min(xi0 + 1, kTW - 1), yi1 = min(yi0 + 1, kTH - 1);
        float wx = fx - (float)xi0, wy = fy - (float)yi0;
        float w00 = (1.0f - wx) * (1.0f - wy) * mk;
        float w01 = wx * (1.0f - wy) * mk;
        float w10 = (1.0f - wx) * wy * mk;
        float w11 = wx * wy * mk;
        s_pxW[tid] = make_float4(w00, w01, w10, w11);   // aliases F0 (dead)
        s_pxO[tid] = make_int4(yi0 * kTW + xi0, yi0 * kTW + xi1,
                               yi1 * kTW + xi0, yi1 * kTW + xi1);
        out[kB * kH * kW * 3 + (b * kH + pyi) * kW + pxi] = improb;
    }
    __syncthreads();

    // ---------- fragment shader: 192 threads = 64 px x 3 channels ----------
    if (tid < 192) {
        int pix = tid & 63;
        int c = tid >> 6;
        float4 w = s_pxW[pix];
        int4 o = s_pxO[pix];
        const float* tc = tex + ((size_t)b * 3 + c) * kTH * kTW;
        float col = tc[o.x] * w.x + tc[o.y] * w.y + tc[o.z] * w.z + tc[o.w] * w.w;
        int qy = ty * 8 + (pix >> 3);
        int qx = tx * 8 + (pix & 7);
        out[((b * kH + qy) * kW + qx) * 3 + c] = col;
    }
}

extern "C" void kernel_launch(void* const* d_in, const int* in_sizes, int n_in,
                              void* d_out, int out_size, void* d_ws, size_t ws_size,
                              hipStream_t stream) {
    const float* pts = (const float*)d_in[0];
    const int* faces = (const int*)d_in[1];
    const float* uvs = (const float*)d_in[2];
    const float* tex = (const float*)d_in[3];
    float* out = (float*)d_out;
    render_all<<<kB * 256, 512, 0, stream>>>(pts, faces, uvs, tex, out);
}